// Round 2
// baseline (463.486 us; speedup 1.0000x reference)
//
#include <hip/hip_runtime.h>
#include <math.h>

#define N_NODES 50000
#define N_EDGES 800000
#define D_FEAT 64

// Order-preserving float->uint map for integer atomicMax on floats.
__device__ __forceinline__ unsigned enc_f(float f) {
    unsigned u = __float_as_uint(f);
    return (u & 0x80000000u) ? ~u : (u | 0x80000000u);
}
__device__ __forceinline__ float dec_f(unsigned u) {
    return __uint_as_float((u & 0x80000000u) ? (u & 0x7fffffffu) : ~u);
}

// 1) per-edge: sq[r] += w^2 ; deg[r] += 1
__global__ void k_edge1(const float* __restrict__ w, const int* __restrict__ row,
                        float* __restrict__ sq, int* __restrict__ deg) {
    int e = blockIdx.x * blockDim.x + threadIdx.x;
    if (e < N_EDGES) {
        float v = w[e];
        int r = row[e];
        atomicAdd(&sq[r], v * v);
        atomicAdd(&deg[r], 1);
    }
}

// 2) xn = row-wise L2 normalized x; amax_enc[i] = enc(beta) (self-loop term)
__global__ void k_node_norm(const float* __restrict__ x, float* __restrict__ xn,
                            unsigned* __restrict__ amax_enc,
                            const float* __restrict__ beta) {
    int i = blockIdx.x * 4 + (threadIdx.x >> 6);
    int lane = threadIdx.x & 63;
    if (i >= N_NODES) return;
    float v = x[i * D_FEAT + lane];
    float s = v * v;
    #pragma unroll
    for (int off = 32; off; off >>= 1) s += __shfl_xor(s, off, 64);
    float inv = 1.0f / fmaxf(sqrtf(s), 1e-12f);
    xn[i * D_FEAT + lane] = v * inv;
    if (lane == 0) amax_enc[i] = enc_f(beta[0]);
}

// 3) per-edge: amax[r] = max(amax[r], beta * w/||.||)
__global__ void k_edge2(const float* __restrict__ w, const int* __restrict__ row,
                        const float* __restrict__ sq, unsigned* __restrict__ amax_enc,
                        const float* __restrict__ beta) {
    int e = blockIdx.x * blockDim.x + threadIdx.x;
    if (e < N_EDGES) {
        int r = row[e];
        float alpha = beta[0] * (w[e] / fmaxf(sqrtf(sq[r]), 1e-12f));
        atomicMax(&amax_enc[r], enc_f(alpha));
    }
}

// 4) single-block exclusive scan of deg -> offs[0..N], and cursor copy
__global__ void __launch_bounds__(1024) k_scan(const int* __restrict__ deg,
                                               int* __restrict__ offs,
                                               int* __restrict__ cursor) {
    __shared__ int parts[1024];
    const int T = 1024;
    const int CHUNK = (N_NODES + T - 1) / T;  // 49
    int t = threadIdx.x;
    int s0 = t * CHUNK;
    int s1 = min(s0 + CHUNK, N_NODES);
    int local = 0;
    for (int i = s0; i < s1; ++i) local += deg[i];
    parts[t] = local;
    __syncthreads();
    // simple Hillis-Steele scan over 1024 partials (inclusive)
    for (int off = 1; off < T; off <<= 1) {
        int v = (t >= off) ? parts[t - off] : 0;
        __syncthreads();
        parts[t] += v;
        __syncthreads();
    }
    int base = (t == 0) ? 0 : parts[t - 1];
    for (int i = s0; i < s1; ++i) {
        offs[i] = base;
        cursor[i] = base;
        base += deg[i];
    }
    if (t == T - 1) offs[N_NODES] = base;
}

// 5) per-edge: ex = exp(alpha - amax); denom[r] += ex; CSR fill
__global__ void k_edge3(const float* __restrict__ w, const int* __restrict__ row,
                        const int* __restrict__ col, const float* __restrict__ sq,
                        const unsigned* __restrict__ amax_enc,
                        float* __restrict__ denom, int* __restrict__ cursor,
                        int* __restrict__ ecol, float* __restrict__ eex,
                        const float* __restrict__ beta) {
    int e = blockIdx.x * blockDim.x + threadIdx.x;
    if (e < N_EDGES) {
        int r = row[e];
        float alpha = beta[0] * (w[e] / fmaxf(sqrtf(sq[r]), 1e-12f));
        float v = expf(alpha - dec_f(amax_enc[r]));
        atomicAdd(&denom[r], v);
        int pos = atomicAdd(&cursor[r], 1);
        ecol[pos] = col[e];
        eex[pos] = v;
    }
}

// 6) gather: one wave per node. out[i] = (1+eps)*xn_i + (self_ex*xn_i + sum a*xn[c]) / denom
__global__ void k_gather(const int* __restrict__ offs, const int* __restrict__ ecol,
                         const float* __restrict__ eex, const float* __restrict__ denom,
                         const unsigned* __restrict__ amax_enc,
                         const float* __restrict__ xn, const float* __restrict__ beta,
                         const float* __restrict__ epsp, float* __restrict__ out) {
    int i = blockIdx.x * 4 + (threadIdx.x >> 6);
    int lane = threadIdx.x & 63;
    if (i >= N_NODES) return;
    int s = offs[i], e = offs[i + 1];
    float self_ex = expf(beta[0] - dec_f(amax_enc[i]));
    float inv = 1.0f / (denom[i] + self_ex + 1e-16f);
    float acc = 0.0f;
    for (int j = s; j < e; ++j) {
        int c = ecol[j];          // wave-broadcast load
        float a = eex[j];         // wave-broadcast load
        acc += a * xn[c * D_FEAT + lane];
    }
    float xi = xn[i * D_FEAT + lane];
    out[i * D_FEAT + lane] = (1.0f + epsp[0]) * xi + (self_ex * xi + acc) * inv;
}

extern "C" void kernel_launch(void* const* d_in, const int* in_sizes, int n_in,
                              void* d_out, int out_size, void* d_ws, size_t ws_size,
                              hipStream_t stream) {
    const float* x         = (const float*)d_in[0];
    const float* edge_attr = (const float*)d_in[1];
    const float* beta      = (const float*)d_in[2];
    const float* eps       = (const float*)d_in[3];
    const int*   ei        = (const int*)d_in[4];
    const int*   row = ei;
    const int*   col = ei + N_EDGES;
    float* out = (float*)d_out;

    // workspace layout (4-byte words):
    // [sq N][denom N][deg N]  <- zeroed together
    // [amax_enc N][offs N+1][cursor N][ecol E][eex E][xn N*64]
    unsigned* ws = (unsigned*)d_ws;
    float*    sq       = (float*)ws;
    float*    denom    = (float*)(ws + N_NODES);
    int*      deg      = (int*)(ws + 2 * N_NODES);
    unsigned* amax_enc = ws + 3 * N_NODES;
    int*      offs     = (int*)(ws + 4 * N_NODES);
    int*      cursor   = (int*)(ws + 5 * N_NODES + 1);
    int*      ecol     = (int*)(ws + 6 * N_NODES + 1);
    float*    eex      = (float*)(ws + 6 * N_NODES + 1 + N_EDGES);
    float*    xn       = (float*)(ws + 6 * N_NODES + 1 + 2 * N_EDGES);

    hipMemsetAsync(sq, 0, 3 * N_NODES * sizeof(float), stream);

    const int TB = 256;
    k_edge1<<<(N_EDGES + TB - 1) / TB, TB, 0, stream>>>(edge_attr, row, sq, deg);
    k_node_norm<<<(N_NODES + 3) / 4, TB, 0, stream>>>(x, xn, amax_enc, beta);
    k_edge2<<<(N_EDGES + TB - 1) / TB, TB, 0, stream>>>(edge_attr, row, sq, amax_enc, beta);
    k_scan<<<1, 1024, 0, stream>>>(deg, offs, cursor);
    k_edge3<<<(N_EDGES + TB - 1) / TB, TB, 0, stream>>>(edge_attr, row, col, sq, amax_enc,
                                                        denom, cursor, ecol, eex, beta);
    k_gather<<<(N_NODES + 3) / 4, TB, 0, stream>>>(offs, ecol, eex, denom, amax_enc,
                                                   xn, beta, eps, out);
}

// Round 3
// 285.336 us; speedup vs baseline: 1.6244x; 1.6244x over previous
//
#include <hip/hip_runtime.h>
#include <math.h>

#define N_NODES 50000
#define N_EDGES 800000
#define D_FEAT 64
#define NB_SCAN ((N_NODES + 255) / 256)   // 196 blocks

// 1) deg[r] += 1 per edge
__global__ void k_deg(const int* __restrict__ row, int* __restrict__ deg) {
    int e = blockIdx.x * blockDim.x + threadIdx.x;
    if (e < N_EDGES) atomicAdd(&deg[row[e]], 1);
}

// 2) xn = row-wise L2 normalized x (one wave per node)
__global__ void k_node_norm(const float* __restrict__ x, float* __restrict__ xn) {
    int i = blockIdx.x * 4 + (threadIdx.x >> 6);
    int lane = threadIdx.x & 63;
    if (i >= N_NODES) return;
    float v = x[i * D_FEAT + lane];
    float s = v * v;
    #pragma unroll
    for (int off = 32; off; off >>= 1) s += __shfl_xor(s, off, 64);
    xn[i * D_FEAT + lane] = v * (1.0f / fmaxf(sqrtf(s), 1e-12f));
}

// 3a) per-block partial sums of deg
__global__ void k_bsum(const int* __restrict__ deg, int* __restrict__ bsum) {
    __shared__ int sm[256];
    int t = threadIdx.x;
    int gid = blockIdx.x * 256 + t;
    sm[t] = (gid < N_NODES) ? deg[gid] : 0;
    __syncthreads();
    for (int off = 128; off; off >>= 1) {
        if (t < off) sm[t] += sm[t + off];
        __syncthreads();
    }
    if (t == 0) bsum[blockIdx.x] = sm[0];
}

// 3b) exclusive scan of the 196 block sums (single tiny block)
__global__ void k_bscan(const int* __restrict__ bsum, int* __restrict__ bbase) {
    __shared__ int sm[256];
    int t = threadIdx.x;
    int v = (t < NB_SCAN) ? bsum[t] : 0;
    sm[t] = v;
    __syncthreads();
    for (int off = 1; off < 256; off <<= 1) {
        int u = (t >= off) ? sm[t - off] : 0;
        __syncthreads();
        sm[t] += u;
        __syncthreads();
    }
    if (t < NB_SCAN) bbase[t] = sm[t] - v;  // exclusive
}

// 3c) per-block local scan + block base -> offs, cursor
__global__ void k_offs(const int* __restrict__ deg, const int* __restrict__ bbase,
                       int* __restrict__ offs, int* __restrict__ cursor) {
    __shared__ int sm[256];
    int t = threadIdx.x;
    int gid = blockIdx.x * 256 + t;
    int v = (gid < N_NODES) ? deg[gid] : 0;
    sm[t] = v;
    __syncthreads();
    for (int off = 1; off < 256; off <<= 1) {
        int u = (t >= off) ? sm[t - off] : 0;
        __syncthreads();
        sm[t] += u;
        __syncthreads();
    }
    if (gid < N_NODES) {
        int ex = bbase[blockIdx.x] + sm[t] - v;
        offs[gid] = ex;
        cursor[gid] = ex;
    }
    if (gid == 0) offs[N_NODES] = N_EDGES;
}

// 4) CSR fill: raw edge weight + col, bucketed by row
__global__ void k_fill(const int* __restrict__ row, const int* __restrict__ col,
                       const float* __restrict__ w, int* __restrict__ cursor,
                       int* __restrict__ ecol, float* __restrict__ ew) {
    int e = blockIdx.x * blockDim.x + threadIdx.x;
    if (e < N_EDGES) {
        int pos = atomicAdd(&cursor[row[e]], 1);
        ecol[pos] = col[e];
        ew[pos] = w[e];
    }
}

// 5) gather: one wave per node computes norm, max, denom, and SpMM locally.
__global__ void k_gather(const int* __restrict__ offs, const int* __restrict__ ecol,
                         const float* __restrict__ ew, const float* __restrict__ xn,
                         const float* __restrict__ beta, const float* __restrict__ epsp,
                         float* __restrict__ out) {
    int i = blockIdx.x * 4 + (threadIdx.x >> 6);
    int lane = threadIdx.x & 63;
    if (i >= N_NODES) return;
    int s = offs[i], e = offs[i + 1];
    float b = beta[0];
    float xi = xn[i * D_FEAT + lane];
    float outv;
    if (s < e) {
        // pass 1: sum of squares + min/max of raw weights (wave-uniform values)
        float sumsq = 0.f, wmax = -1e30f, wmin = 1e30f;
        for (int j = s; j < e; ++j) {
            float w = ew[j];
            sumsq += w * w;
            wmax = fmaxf(wmax, w);
            wmin = fminf(wmin, w);
        }
        float inv_norm = 1.0f / fmaxf(sqrtf(sumsq), 1e-12f);
        // alpha_j = b * w_j * inv_norm; segment max incl. self-loop alpha = b
        float m = fmaxf(b, fmaxf(b * wmax, b * wmin) * inv_norm);
        float self_ex = expf(b - m);
        float denom = self_ex;
        float acc = 0.f;
        // pass 2: exp, denom, weighted feature gather
        for (int j = s; j < e; ++j) {
            float exv = expf(b * ew[j] * inv_norm - m);
            denom += exv;
            acc += exv * xn[ecol[j] * D_FEAT + lane];
        }
        float invd = 1.0f / (denom + 1e-16f);
        outv = (1.0f + epsp[0]) * xi + (self_ex * xi + acc) * invd;
    } else {
        // no in-edges: softmax over the single self-loop = 1/(1+1e-16)
        outv = (1.0f + epsp[0]) * xi + xi / (1.0f + 1e-16f);
    }
    out[i * D_FEAT + lane] = outv;
}

extern "C" void kernel_launch(void* const* d_in, const int* in_sizes, int n_in,
                              void* d_out, int out_size, void* d_ws, size_t ws_size,
                              hipStream_t stream) {
    const float* x         = (const float*)d_in[0];
    const float* edge_attr = (const float*)d_in[1];
    const float* beta      = (const float*)d_in[2];
    const float* eps       = (const float*)d_in[3];
    const int*   ei        = (const int*)d_in[4];
    const int*   row = ei;
    const int*   col = ei + N_EDGES;
    float* out = (float*)d_out;

    // workspace (4-byte words):
    // deg[N] | offs[N+1] | cursor[N] | bsum[NB] | bbase[NB] | ecol[E] | ew[E] | xn[N*64]
    unsigned* ws = (unsigned*)d_ws;
    int*   deg    = (int*)ws;
    int*   offs   = (int*)(ws + N_NODES);
    int*   cursor = (int*)(ws + 2 * N_NODES + 1);
    int*   bsum   = (int*)(ws + 3 * N_NODES + 1);
    int*   bbase  = (int*)(ws + 3 * N_NODES + 1 + NB_SCAN);
    int*   ecol   = (int*)(ws + 3 * N_NODES + 1 + 2 * NB_SCAN);
    float* ew     = (float*)(ws + 3 * N_NODES + 1 + 2 * NB_SCAN + N_EDGES);
    float* xn     = (float*)(ws + 3 * N_NODES + 1 + 2 * NB_SCAN + 2 * N_EDGES);

    hipMemsetAsync(deg, 0, N_NODES * sizeof(int), stream);

    const int TB = 256;
    k_deg<<<(N_EDGES + TB - 1) / TB, TB, 0, stream>>>(row, deg);
    k_node_norm<<<(N_NODES + 3) / 4, TB, 0, stream>>>(x, xn);
    k_bsum<<<NB_SCAN, TB, 0, stream>>>(deg, bsum);
    k_bscan<<<1, TB, 0, stream>>>(bsum, bbase);
    k_offs<<<NB_SCAN, TB, 0, stream>>>(deg, bbase, offs, cursor);
    k_fill<<<(N_EDGES + TB - 1) / TB, TB, 0, stream>>>(row, col, edge_attr, cursor, ecol, ew);
    k_gather<<<(N_NODES + 3) / 4, TB, 0, stream>>>(offs, ecol, ew, xn, beta, eps, out);
}

// Round 4
// 207.067 us; speedup vs baseline: 2.2383x; 1.3780x over previous
//
#include <hip/hip_runtime.h>
#include <math.h>

#define N_NODES 50000
#define N_EDGES 800000
#define D_FEAT 64
#define NB_SCAN ((N_NODES + 255) / 256)          // 196 blocks for node-indexed passes
#define EDGE_BLOCKS (N_EDGES / 256)              // 3125 (exact)
#define NORM_BLOCKS (N_NODES / 16)               // 3125 (exact): 16 nodes/block, float4 lanes

// 1) fused: node L2-norm (float4, 4 nodes/wave) + edge degree count
__global__ void k_pre(const float* __restrict__ x, float* __restrict__ xn,
                      const int* __restrict__ row, int* __restrict__ deg) {
    int b = blockIdx.x;
    if (b < NORM_BLOCKS) {
        // 16 nodes per block: node = b*16 + (tid>>4), lanes l16 hold float4
        int n = b * 16 + (threadIdx.x >> 4);
        int l16 = threadIdx.x & 15;
        float4 v = ((const float4*)x)[n * 16 + l16];
        float s = v.x * v.x + v.y * v.y + v.z * v.z + v.w * v.w;
        #pragma unroll
        for (int off = 1; off < 16; off <<= 1) s += __shfl_xor(s, off, 64);
        float inv = 1.0f / fmaxf(sqrtf(s), 1e-12f);
        float4 o; o.x = v.x * inv; o.y = v.y * inv; o.z = v.z * inv; o.w = v.w * inv;
        ((float4*)xn)[n * 16 + l16] = o;
    } else {
        int e = (b - NORM_BLOCKS) * 256 + threadIdx.x;   // exact: no guard
        atomicAdd(&deg[row[e]], 1);
    }
}

// 2) per-block partial sums of deg
__global__ void k_bsum(const int* __restrict__ deg, int* __restrict__ bsum) {
    __shared__ int sm[256];
    int t = threadIdx.x;
    int gid = blockIdx.x * 256 + t;
    sm[t] = (gid < N_NODES) ? deg[gid] : 0;
    __syncthreads();
    for (int off = 128; off; off >>= 1) {
        if (t < off) sm[t] += sm[t + off];
        __syncthreads();
    }
    if (t == 0) bsum[blockIdx.x] = sm[0];
}

// 3) offs/cursor: inline exclusive-prefix of bsum + per-block scan of deg
__global__ void k_offs(const int* __restrict__ deg, const int* __restrict__ bsum,
                       int* __restrict__ offs, int* __restrict__ cursor) {
    __shared__ int sm[256];
    __shared__ int base_sh;
    int t = threadIdx.x;
    // phase 1: base = sum of bsum[0..blockIdx)
    sm[t] = (t < blockIdx.x) ? bsum[t] : 0;
    __syncthreads();
    for (int off = 128; off; off >>= 1) {
        if (t < off) sm[t] += sm[t + off];
        __syncthreads();
    }
    if (t == 0) base_sh = sm[0];
    __syncthreads();
    // phase 2: inclusive scan of this block's deg
    int gid = blockIdx.x * 256 + t;
    int v = (gid < N_NODES) ? deg[gid] : 0;
    sm[t] = v;
    __syncthreads();
    for (int off = 1; off < 256; off <<= 1) {
        int u = (t >= off) ? sm[t - off] : 0;
        __syncthreads();
        sm[t] += u;
        __syncthreads();
    }
    if (gid < N_NODES) {
        int ex = base_sh + sm[t] - v;
        offs[gid] = ex;
        cursor[gid] = ex;
    }
    if (gid == 0) offs[N_NODES] = N_EDGES;
}

// 4) CSR fill: packed (col, w_bits) single 8B store per edge
__global__ void k_fill(const int* __restrict__ row, const int* __restrict__ col,
                       const float* __restrict__ w, int* __restrict__ cursor,
                       uint2* __restrict__ epack) {
    int e = blockIdx.x * 256 + threadIdx.x;   // exact grid, no guard
    int pos = atomicAdd(&cursor[row[e]], 1);
    uint2 p; p.x = (unsigned)col[e]; p.y = __float_as_uint(w[e]);
    epack[pos] = p;
}

// 5) gather: one wave/node; 4 edge-groups of 16 lanes, float4 features
__global__ void k_gather(const int* __restrict__ offs, const uint2* __restrict__ epack,
                         const float* __restrict__ xn, const float* __restrict__ beta,
                         const float* __restrict__ epsp, float* __restrict__ out) {
    int i = blockIdx.x * 4 + (threadIdx.x >> 6);
    int lane = threadIdx.x & 63;
    int grp = lane >> 4;
    int l16 = lane & 15;
    int s = offs[i], e = offs[i + 1];
    float b = beta[0];

    // pass 1: sumsq / wmax / wmin, 64-lane strided
    float sumsq = 0.f, wmax = -1e30f, wmin = 1e30f;
    for (int j = s + lane; j < e; j += 64) {
        float w = __uint_as_float(epack[j].y);
        sumsq += w * w;
        wmax = fmaxf(wmax, w);
        wmin = fminf(wmin, w);
    }
    #pragma unroll
    for (int off = 32; off; off >>= 1) {
        sumsq += __shfl_xor(sumsq, off, 64);
        wmax = fmaxf(wmax, __shfl_xor(wmax, off, 64));
        wmin = fminf(wmin, __shfl_xor(wmin, off, 64));
    }
    float inv_norm = 1.0f / fmaxf(sqrtf(sumsq), 1e-12f);
    float m = (s < e) ? fmaxf(b, fmaxf(b * wmax, b * wmin) * inv_norm) : b;
    float self_ex = expf(b - m);

    // pass 2: each 16-lane group handles one edge per trip, float4 features
    float4 acc; acc.x = acc.y = acc.z = acc.w = 0.f;
    float dpart = 0.f;
    for (int k = s + grp; k < e; k += 4) {
        uint2 p = epack[k];                          // broadcast within group
        float w = __uint_as_float(p.y);
        float exv = expf(b * w * inv_norm - m);
        dpart += exv;
        float4 xv = ((const float4*)(xn + (size_t)p.x * D_FEAT))[l16];
        acc.x += exv * xv.x; acc.y += exv * xv.y;
        acc.z += exv * xv.z; acc.w += exv * xv.w;
    }
    // reduce across the 4 groups
    #pragma unroll
    for (int off = 16; off <= 32; off <<= 1) {
        acc.x += __shfl_xor(acc.x, off, 64);
        acc.y += __shfl_xor(acc.y, off, 64);
        acc.z += __shfl_xor(acc.z, off, 64);
        acc.w += __shfl_xor(acc.w, off, 64);
        dpart += __shfl_xor(dpart, off, 64);
    }
    float invd = 1.0f / (dpart + self_ex + 1e-16f);
    float4 xi = ((const float4*)(xn + (size_t)i * D_FEAT))[l16];
    float c0 = 1.0f + epsp[0];
    float4 o;
    o.x = c0 * xi.x + (self_ex * xi.x + acc.x) * invd;
    o.y = c0 * xi.y + (self_ex * xi.y + acc.y) * invd;
    o.z = c0 * xi.z + (self_ex * xi.z + acc.z) * invd;
    o.w = c0 * xi.w + (self_ex * xi.w + acc.w) * invd;
    if (grp == 0) ((float4*)(out + (size_t)i * D_FEAT))[l16] = o;
}

extern "C" void kernel_launch(void* const* d_in, const int* in_sizes, int n_in,
                              void* d_out, int out_size, void* d_ws, size_t ws_size,
                              hipStream_t stream) {
    const float* x         = (const float*)d_in[0];
    const float* edge_attr = (const float*)d_in[1];
    const float* beta      = (const float*)d_in[2];
    const float* eps       = (const float*)d_in[3];
    const int*   ei        = (const int*)d_in[4];
    const int*   row = ei;
    const int*   col = ei + N_EDGES;
    float* out = (float*)d_out;

    // ws words: deg[N] | offs[N+1] | cursor[N] | bsum[196] | pad | epack[2E] | xn[N*64]
    unsigned* ws = (unsigned*)d_ws;
    int*   deg    = (int*)ws;
    int*   offs   = (int*)(ws + N_NODES);
    int*   cursor = (int*)(ws + 2 * N_NODES + 1);
    int*   bsum   = (int*)(ws + 3 * N_NODES + 1);
    uint2* epack  = (uint2*)(ws + 3 * N_NODES + 1 + NB_SCAN + 1);   // 8B aligned (word off even)
    float* xn     = (float*)(ws + 3 * N_NODES + 1 + NB_SCAN + 1 + 2 * N_EDGES);

    hipMemsetAsync(deg, 0, N_NODES * sizeof(int), stream);

    const int TB = 256;
    k_pre<<<NORM_BLOCKS + EDGE_BLOCKS, TB, 0, stream>>>(x, xn, row, deg);
    k_bsum<<<NB_SCAN, TB, 0, stream>>>(deg, bsum);
    k_offs<<<NB_SCAN, TB, 0, stream>>>(deg, bsum, offs, cursor);
    k_fill<<<EDGE_BLOCKS, TB, 0, stream>>>(row, col, edge_attr, cursor, epack);
    k_gather<<<(N_NODES + 3) / 4, TB, 0, stream>>>(offs, epack, xn, beta, eps, out);
}